// Round 10
// baseline (700.052 us; speedup 1.0000x reference)
//
#include <hip/hip_runtime.h>

// DIN attention unit, MI355X — round 16: materialize the prefetch + pk-FMA.
// R15 post-mortem: VGPR=52 proves the 2-deep queue never materialized (a
// 2-deep float4 queue alone is 40 VGPR) — the compiler sank loads to their
// use points; PIN anchors the wait, not the issue. VALUBusy 67% x 68us =
// 45us pure VALU issue => now mostly issue-bound. Two fixes:
//  (1) __builtin_amdgcn_sched_barrier(0) right after each load cluster
//      pins the ISSUE point; counted vmcnt waits still land at first use.
//  (2) v_pk_fma_f32 (CDNA packed dual-FMA): the 20-deep d-loop -> 10
//      packed FMAs/channel. Key pairs are free (float4 halves are aligned
//      VGPR pairs); weight pairs via "s" constraint (uniform s_load_x2,
//      one SGPR operand = legal). Tower issue 640 -> 320 slots/row.
// Everything else: R15's proven structure (fp32, 4 dispatches, scalar
// weight path, AGENT-scope stat readback, 8-slot atomics).
// mask input UNUSED (reference uses unmasked scores — reproduced bug).

#define BB 512
#define TT 2048
#define DD 20
#define C0 32
#define C1 16

#define NTH 256              // 4 waves/block
#define CHUNK 1024           // rows per block (4 rows/thread)
#define NBLK (TT / CHUNK)    // 2 blocks per batch
#define GRID (BB * NBLK)     // 1024 blocks = 4 per CU
#define NSLOT 8              // atomic slot-split

// ws float offsets
#define WS_P1 0              // 8 slots * (32 sum + 32 sq)
#define WS_P2 512            // 8 slots * (16 sum + 16 sq)
#define WS_ZERO_N 768
#define WS_BLOB 896
#define BLOB_J 24            // 20 wM + c + pad
#define BLOB_B (C0 * BLOB_J)

#define AGLOAD(p) \
    __hip_atomic_load((p), __ATOMIC_RELAXED, __HIP_MEMORY_SCOPE_AGENT)
#define SCHED_FENCE() __builtin_amdgcn_sched_barrier(0)

__device__ __forceinline__ float fast_sigmoid(float x) {
    return __builtin_amdgcn_rcpf(1.0f + __expf(-x));
}

// ---- f32x2 pair helpers (double = aligned VGPR/SGPR pair carrier) ----
__device__ __forceinline__ double mkpair(float lo, float hi) {
    union { float f[2]; double d; } u_;
    u_.f[0] = lo;
    u_.f[1] = hi;
    return u_.d;
}
__device__ __forceinline__ float plo(double d) {
    union { double dd; float f[2]; } u_;
    u_.dd = d;
    return u_.f[0];
}
__device__ __forceinline__ float phi(double d) {
    union { double dd; float f[2]; } u_;
    u_.dd = d;
    return u_.f[1];
}

// Issue 5 float4 loads for one 80B key row into a register slot.
__device__ __forceinline__ void load5(const float* __restrict__ row,
                                      float4 (&P)[5]) {
    const float4* k4 = (const float4*)row;  // rows are 80B => 16B aligned
    P[0] = k4[0];
    P[1] = k4[1];
    P[2] = k4[2];
    P[3] = k4[3];
    P[4] = k4[4];
}

// Repack slot into 10 f32x2 pairs (pure register-pair bitcasts).
__device__ __forceinline__ void mk10(const float4 (&P)[5], double (&k2)[10]) {
#pragma unroll
    for (int u = 0; u < 5; ++u) {
        k2[u * 2 + 0] = mkpair(P[u].x, P[u].y);
        k2[u * 2 + 1] = mkpair(P[u].z, P[u].w);
    }
}

// Packed-FMA tower dot: h = cj + sum_d kk[d]*wM[d], weights on scalar bus.
__device__ __forceinline__ float dot20_pk(const double (&k2)[10],
                                          const float* __restrict__ wr) {
    const double* w2 = (const double*)wr;  // 8B-aligned (96B row stride)
    double acc = mkpair(wr[20], 0.0f);     // cj in lo half
#pragma unroll
    for (int t = 0; t < 10; ++t)
        asm("v_pk_fma_f32 %0, %1, %2, %0"
            : "+v"(acc)
            : "v"(k2[t]), "s"(w2[t]));
    return plo(acc) + phi(acc);
}

// ---------------- prep: fold query into layer-1 weights ----------------
__global__ void prep_kernel(const float* __restrict__ query,
                            const float* __restrict__ W0,
                            const float* __restrict__ b0,
                            float* __restrict__ blob, float* __restrict__ ws,
                            float* __restrict__ out) {
    const int b = blockIdx.x * 2 + (threadIdx.x >> 5);
    const int j = threadIdx.x & 31;
    if (blockIdx.x == 0) {
        for (int i = threadIdx.x; i < WS_ZERO_N; i += 64) ws[i] = 0.f;
    }
    if (j < DD) out[b * DD + j] = 0.f;
    float cj = b0[j];
    float* dst = blob + (size_t)b * BLOB_B + j * BLOB_J;
#pragma unroll
    for (int d = 0; d < DD; ++d) {
        float w_q = W0[d * C0 + j];
        float w_k = W0[(DD + d) * C0 + j];
        float w_d = W0[(2 * DD + d) * C0 + j];
        float w_p = W0[(3 * DD + d) * C0 + j];
        float qd = query[b * DD + d];
        dst[d] = w_k - w_d + qd * w_p;
        cj = fmaf(qd, w_q + w_d, cj);
    }
    dst[20] = cj;
}

// ================= finalize helpers =================
__device__ __forceinline__ void finalize0(int tid, float* __restrict__ ws,
                                          float2* __restrict__ lss0) {
    if (tid < C0) {
        float sv = 0.f, qv = 0.f;
#pragma unroll
        for (int k = 0; k < NSLOT; ++k) {
            sv += AGLOAD(&ws[WS_P1 + k * (2 * C0) + tid]);
            qv += AGLOAD(&ws[WS_P1 + k * (2 * C0) + C0 + tid]);
        }
        const float invN = 1.0f / (float)(BB * TT);
        float mean = sv * invN;
        float var = qv * invN - mean * mean;
        float sc = rsqrtf(var + 1e-9f);
        lss0[tid] = make_float2(sc, -mean * sc);
    }
}

__device__ __forceinline__ void finalize1(int tid, float* __restrict__ ws,
                                          const float* __restrict__ a1,
                                          const float* __restrict__ wk,
                                          float4* __restrict__ ld1v) {
    if (tid < C1) {
        float sv = 0.f, qv = 0.f;
#pragma unroll
        for (int k = 0; k < NSLOT; ++k) {
            sv += AGLOAD(&ws[WS_P2 + k * (2 * C1) + tid]);
            qv += AGLOAD(&ws[WS_P2 + k * (2 * C1) + C1 + tid]);
        }
        const float invN = 1.0f / (float)(BB * TT);
        float mean = sv * invN;
        float var = qv * invN - mean * mean;
        float sc = rsqrtf(var + 1e-9f);
        ld1v[tid] = make_float4(sc, -mean * sc, a1[tid], wk[tid]);
    }
}

// ---------------- pass 1: layer-1 pre-activation stats ----------------
__device__ __forceinline__ void p1row(const float4 (&P)[5],
                                      const float* __restrict__ bA,
                                      float (&s)[C0], float (&q)[C0]) {
    double k2[10];
    mk10(P, k2);
#pragma unroll
    for (int j = 0; j < C0; ++j) {
        float hh = dot20_pk(k2, bA + j * BLOB_J);
        s[j] += hh;
        q[j] = fmaf(hh, hh, q[j]);
    }
}

__global__ __launch_bounds__(NTH, 2) void pass1_kernel(
    const float* __restrict__ keys, const float* __restrict__ blob,
    float* __restrict__ ws) {
    const int batch = blockIdx.x >> 1, chunk = blockIdx.x & 1;
    const int slot = blockIdx.x & (NSLOT - 1);
    const int tid = threadIdx.x, lane = tid & 63;
    const float* bA = blob + (size_t)batch * BLOB_B;
    const float* kbase = keys + ((size_t)batch * TT + chunk * CHUNK) * DD;

    float s[C0], q[C0];
#pragma unroll
    for (int j = 0; j < C0; ++j) { s[j] = 0.f; q[j] = 0.f; }

    // 4 rows/thread, 2-deep queue; sched_barrier pins the ISSUE points.
    float4 A[5], B[5];
    load5(kbase + (size_t)tid * DD, A);
    load5(kbase + (size_t)(tid + NTH) * DD, B);
    SCHED_FENCE();
    p1row(A, bA, s, q);
    load5(kbase + (size_t)(tid + 2 * NTH) * DD, A);
    SCHED_FENCE();
    p1row(B, bA, s, q);
    load5(kbase + (size_t)(tid + 3 * NTH) * DD, B);
    SCHED_FENCE();
    p1row(A, bA, s, q);
    p1row(B, bA, s, q);

    float redv = 0.f;
#pragma unroll
    for (int v = 0; v < 2 * C0; ++v) {
        float val = (v < C0) ? s[v] : q[v - C0];
#pragma unroll
        for (int o = 32; o >= 1; o >>= 1) val += __shfl_xor(val, o);
        if (lane == v) redv = val;
    }
    atomicAdd(&ws[WS_P1 + slot * (2 * C0) + lane], redv);
}

// ---------------- pass 2: layer-2 pre-activation stats ----------------
__device__ __forceinline__ void p2row(const float4 (&P)[5],
                                      const float* __restrict__ bA,
                                      const float* __restrict__ a0,
                                      const float* __restrict__ W1,
                                      const float* __restrict__ b1,
                                      const float2* __restrict__ lss0,
                                      float (&s1)[C1], float (&q1)[C1]) {
    double k2[10];
    mk10(P, k2);
    float h1[C1];
#pragma unroll
    for (int c = 0; c < C1; ++c) h1[c] = 0.f;
#pragma unroll
    for (int j = 0; j < C0; ++j) {
        float hh = dot20_pk(k2, bA + j * BLOB_J);
        const float2 ss = lss0[j];
        const float al = a0[j];
        float pr = fast_sigmoid(fmaf(hh, ss.x, ss.y));
        float gg = hh * fmaf(pr, 1.0f - al, al);
        const float* ur = W1 + j * C1;
#pragma unroll
        for (int c = 0; c < C1; ++c) h1[c] = fmaf(gg, ur[c], h1[c]);
    }
#pragma unroll
    for (int c = 0; c < C1; ++c) {
        float v = h1[c] + b1[c];
        s1[c] += v;
        q1[c] = fmaf(v, v, q1[c]);
    }
}

__global__ __launch_bounds__(NTH, 2) void pass2_kernel(
    const float* __restrict__ keys, const float* __restrict__ blob,
    const float* __restrict__ a0, const float* __restrict__ W1,
    const float* __restrict__ b1, float* __restrict__ ws) {
    const int batch = blockIdx.x >> 1, chunk = blockIdx.x & 1;
    const int slot = blockIdx.x & (NSLOT - 1);
    const int tid = threadIdx.x, lane = tid & 63;
    const float* bA = blob + (size_t)batch * BLOB_B;
    const float* kbase = keys + ((size_t)batch * TT + chunk * CHUNK) * DD;
    __shared__ float2 lss0[C0];
    finalize0(tid, ws, lss0);
    __syncthreads();

    float s1[C1], q1[C1];
#pragma unroll
    for (int c = 0; c < C1; ++c) { s1[c] = 0.f; q1[c] = 0.f; }

    float4 A[5], B[5];
    load5(kbase + (size_t)tid * DD, A);
    load5(kbase + (size_t)(tid + NTH) * DD, B);
    SCHED_FENCE();
    p2row(A, bA, a0, W1, b1, lss0, s1, q1);
    load5(kbase + (size_t)(tid + 2 * NTH) * DD, A);
    SCHED_FENCE();
    p2row(B, bA, a0, W1, b1, lss0, s1, q1);
    load5(kbase + (size_t)(tid + 3 * NTH) * DD, B);
    SCHED_FENCE();
    p2row(A, bA, a0, W1, b1, lss0, s1, q1);
    p2row(B, bA, a0, W1, b1, lss0, s1, q1);

    float redv = 0.f;
#pragma unroll
    for (int v = 0; v < 2 * C1; ++v) {
        float val = (v < C1) ? s1[v] : q1[v - C1];
#pragma unroll
        for (int o = 32; o >= 1; o >>= 1) val += __shfl_xor(val, o);
        if (lane == v) redv = val;
    }
    if (lane < 2 * C1)
        atomicAdd(&ws[WS_P2 + slot * (2 * C1) + lane], redv);
}

// ---------------- pass 3: full tower + weighted key-sum ----------------
__device__ __forceinline__ void p3row(
    const float4 (&P)[5], const float* __restrict__ bA,
    const float* __restrict__ a0, const float* __restrict__ W1,
    const float* __restrict__ b1, const float2* __restrict__ lss0,
    const float4* __restrict__ ld1v, float bkv, float (&oacc)[DD]) {
    double k2[10];
    mk10(P, k2);
    float h1[C1];
#pragma unroll
    for (int c = 0; c < C1; ++c) h1[c] = 0.f;
#pragma unroll
    for (int j = 0; j < C0; ++j) {
        float hh = dot20_pk(k2, bA + j * BLOB_J);
        const float2 ss = lss0[j];
        const float al = a0[j];
        float pr = fast_sigmoid(fmaf(hh, ss.x, ss.y));
        float gg = hh * fmaf(pr, 1.0f - al, al);
        const float* ur = W1 + j * C1;
#pragma unroll
        for (int c = 0; c < C1; ++c) h1[c] = fmaf(gg, ur[c], h1[c]);
    }
    float score = bkv;
#pragma unroll
    for (int c = 0; c < C1; ++c) {
        float v = h1[c] + b1[c];
        float4 dv = ld1v[c];
        float pr = fast_sigmoid(fmaf(v, dv.x, dv.y));
        float hd = v * fmaf(pr, 1.0f - dv.z, dv.z);
        score = fmaf(hd, dv.w, score);
    }
#pragma unroll
    for (int u = 0; u < 5; ++u) {
        oacc[u * 4 + 0] = fmaf(score, P[u].x, oacc[u * 4 + 0]);
        oacc[u * 4 + 1] = fmaf(score, P[u].y, oacc[u * 4 + 1]);
        oacc[u * 4 + 2] = fmaf(score, P[u].z, oacc[u * 4 + 2]);
        oacc[u * 4 + 3] = fmaf(score, P[u].w, oacc[u * 4 + 3]);
    }
}

__global__ __launch_bounds__(NTH, 2) void pass3_kernel(
    const float* __restrict__ keys, const float* __restrict__ blob,
    const float* __restrict__ a0, const float* __restrict__ W1,
    const float* __restrict__ b1, const float* __restrict__ a1,
    const float* __restrict__ wk, const float* __restrict__ bk,
    float* __restrict__ ws, float* __restrict__ out) {
    const int batch = blockIdx.x >> 1, chunk = blockIdx.x & 1;
    const int tid = threadIdx.x, wave = tid >> 6, lane = tid & 63;
    const float* bA = blob + (size_t)batch * BLOB_B;
    const float* kbase = keys + ((size_t)batch * TT + chunk * CHUNK) * DD;
    __shared__ float2 lss0[C0];
    __shared__ float4 ld1v[C1];
    __shared__ float red[4][DD];
    finalize0(tid, ws, lss0);
    finalize1(tid, ws, a1, wk, ld1v);
    __syncthreads();

    const float bkv = bk[0];
    float oacc[DD];
#pragma unroll
    for (int d = 0; d < DD; ++d) oacc[d] = 0.f;

    float4 A[5], B[5];
    load5(kbase + (size_t)tid * DD, A);
    load5(kbase + (size_t)(tid + NTH) * DD, B);
    SCHED_FENCE();
    p3row(A, bA, a0, W1, b1, lss0, ld1v, bkv, oacc);
    load5(kbase + (size_t)(tid + 2 * NTH) * DD, A);
    SCHED_FENCE();
    p3row(B, bA, a0, W1, b1, lss0, ld1v, bkv, oacc);
    load5(kbase + (size_t)(tid + 3 * NTH) * DD, B);
    SCHED_FENCE();
    p3row(A, bA, a0, W1, b1, lss0, ld1v, bkv, oacc);
    p3row(B, bA, a0, W1, b1, lss0, ld1v, bkv, oacc);

    float redv = 0.f;
#pragma unroll
    for (int v = 0; v < DD; ++v) {
        float val = oacc[v];
#pragma unroll
        for (int o = 32; o >= 1; o >>= 1) val += __shfl_xor(val, o);
        if (lane == v) redv = val;
    }
    if (lane < DD) red[wave][lane] = redv;
    __syncthreads();
    if (tid < DD)
        atomicAdd(&out[batch * DD + tid],
                  red[0][tid] + red[1][tid] + red[2][tid] + red[3][tid]);
}

extern "C" void kernel_launch(void* const* d_in, const int* in_sizes, int n_in,
                              void* d_out, int out_size, void* d_ws,
                              size_t ws_size, hipStream_t stream) {
    const float* keys = (const float*)d_in[0];
    const float* query = (const float*)d_in[1];
    // d_in[2] = mask: intentionally unused
    const float* W0 = (const float*)d_in[3];
    const float* b0 = (const float*)d_in[4];
    const float* a0 = (const float*)d_in[5];
    const float* W1 = (const float*)d_in[6];
    const float* b1 = (const float*)d_in[7];
    const float* a1 = (const float*)d_in[8];
    const float* wk = (const float*)d_in[9];
    const float* bk = (const float*)d_in[10];
    float* out = (float*)d_out;
    float* ws = (float*)d_ws;
    float* blob = ws + WS_BLOB;

    prep_kernel<<<BB / 2, 64, 0, stream>>>(query, W0, b0, blob, ws, out);
    pass1_kernel<<<GRID, NTH, 0, stream>>>(keys, blob, ws);
    pass2_kernel<<<GRID, NTH, 0, stream>>>(keys, blob, a0, W1, b1, ws);
    pass3_kernel<<<GRID, NTH, 0, stream>>>(keys, blob, a0, W1, b1, a1, wk,
                                           bk, ws, out);
}